// Round 2
// baseline (471.747 us; speedup 1.0000x reference)
//
#include <hip/hip_runtime.h>

// channel_attention: einsum('bocs,bocm->bocs', x, softmax(score)) contracts m which
// only appears in score => multiplies x by softmax row-sum == 1 (within fp32 eps).
// So q/k/atten are dead code and the problem is exactly:
//   out[g,c,s] = LN_c( sum_m Wp[c][m] * x[g][m][s] + bp[c] ) * gp[c] + betap[c]
// g = b*o in [0,128). Per group: GEMM M=C=128, N=3000, K=128, + per-column LN.
//
// V3 vs V2 (168us/dispatch, occ 37.5%, HBM 2.3 TB/s -- latency-bound):
//  - NT 128->64: acc 64->32 VGPR, LDS 32->16 KB, staging is ONE 8-load batch
//    (one exposed HBM latency, was two). __launch_bounds__(256,6) -> 6 blocks/CU,
//    24 waves/CU (occupancy 37.5% -> ~75%). This is the TLP play: the problem is
//    pure streaming (floor ~62us), only wave count hides ~900cy HBM latency.
//  - Nontemporal f4 stores: V2's WRITE_SIZE inflated 192->251 MB (dirty partial
//    lines from 16B-aligned rows evicted before fully covered, rewritten). nt
//    flag = no L2 allocate, each sector streams out once, and frees L2 for x.
//  - W stays in global (L1-resident, 32 KB); MFMA D = [s][c] so f4 acc = 4
//    consecutive s at one c; LN reduce via shfl_xor 1/2/4/8 over col lanes.

#define C    128
#define SEQ  3000
#define NG   128
#define NT   64                        // columns per block
#define NBLK ((SEQ + NT - 1) / NT)     // 47

typedef float f4 __attribute__((ext_vector_type(4)));
typedef short short8 __attribute__((ext_vector_type(8)));

__device__ __forceinline__ unsigned short f2bf(float f) {
    union { float f; unsigned u; } v; v.f = f;
    unsigned r = v.u + 0x7fffu + ((v.u >> 16) & 1u);   // RNE
    return (unsigned short)(r >> 16);
}

// packed f32x2 -> bf16x2, RNE; dst.lo = bf16(lo), dst.hi = bf16(hi)
__device__ __forceinline__ unsigned cvt2(float lo, float hi) {
    unsigned r;
    asm("v_cvt_pk_bf16_f32 %0, %1, %2" : "=v"(r) : "v"(lo), "v"(hi));
    return r;
}

// 16B-chunk XOR swizzle: injective over 16 consecutive rows (frag reads) and over
// the transpose-write lane pattern, both verified <=2-way.
__device__ __forceinline__ int swz(int row, int chunk) {
    return chunk ^ ((row ^ (row >> 2)) & 15);
}

__global__ void cvt_wp(const float* __restrict__ Wp, unsigned short* __restrict__ out) {
    int i = blockIdx.x * 256 + threadIdx.x;
    if (i < C * C) out[i] = f2bf(Wp[i]);
}

__global__ __launch_bounds__(256, 6) void gemm_ln_mfma(
    const float* __restrict__ x,             // [NG][C][SEQ] fp32
    const unsigned short* __restrict__ wbf,  // [C][C] bf16 (c-major, m contiguous)
    const float* __restrict__ bp,
    const float* __restrict__ gp,
    const float* __restrict__ bep,
    float* __restrict__ out)                 // [NG][C][SEQ] fp32
{
    __shared__ __align__(16) unsigned short Xl[NT * C];  // 16 KB, [s][m] swizzled

    const int g  = blockIdx.y;
    const int s0 = blockIdx.x * NT;
    const float* xg = x + (size_t)g * (C * SEQ);
    float* og = out + (size_t)g * (C * SEQ);
    const int t = threadIdx.x;

    // ---- stage X transposed: thread owns (m-chunk, s-quad); 8x4 in-register
    // transpose; single batch of 8 f4 loads (one vmcnt wait), 4 x 16B LDS writes.
    {
        const int sq  = t & 15;              // s-quad 0..15 (consecutive lanes -> coalesced)
        const int mc  = t >> 4;              // m-chunk 0..15
        const int s_loc  = 4 * sq;
        const int s_glob = s0 + s_loc;
        const bool valid = (s_glob + 3) < SEQ;
        f4 r[8];
        const float* xp = xg + (size_t)(mc * 8) * SEQ + s_glob;
        #pragma unroll
        for (int rr = 0; rr < 8; ++rr) {
            if (valid) r[rr] = *(const f4*)(xp + (size_t)rr * SEQ);
            else       r[rr] = (f4){0.f, 0.f, 0.f, 0.f};
        }
        #pragma unroll
        for (int j = 0; j < 4; ++j) {
            const int sl = s_loc + j;
            uint4 pk;
            pk.x = cvt2(r[0][j], r[1][j]);
            pk.y = cvt2(r[2][j], r[3][j]);
            pk.z = cvt2(r[4][j], r[5][j]);
            pk.w = cvt2(r[6][j], r[7][j]);
            *(uint4*)&Xl[sl * C + swz(sl, mc) * 8] = pk;
        }
    }
    __syncthreads();

    // ---- MFMA: wave owns 16-row s-strip x all 128 channels (LN fully in-wave).
    // A = X^T (M=s, from LDS), B = W^T (N=c, straight from global; L1-resident).
    // D[s][c]: col(lane&15)=c-tile-idx, row(4*quad+r)=s -> f4 acc = 4 consecutive s.
    const int w    = t >> 6;
    const int lane = t & 63;
    const int col  = lane & 15;
    const int quad = lane >> 4;

    f4 acc[8];   // [mt = c-tile]
    #pragma unroll
    for (int mt = 0; mt < 8; ++mt) acc[mt] = (f4){0.f, 0.f, 0.f, 0.f};

    const unsigned short* wl = wbf + col * C + quad * 8;
    const int srow = 16 * w + col;

    #pragma unroll 1
    for (int kc = 0; kc < 4; ++kc) {
        short8 a = *(const short8*)&Xl[srow * C + swz(srow, 4 * kc + quad) * 8];
        short8 b[8];
        #pragma unroll
        for (int mt = 0; mt < 8; ++mt)
            b[mt] = *(const short8*)(wl + mt * 16 * C + kc * 32);
        #pragma unroll
        for (int mt = 0; mt < 8; ++mt)
            acc[mt] = __builtin_amdgcn_mfma_f32_16x16x32_bf16(a, b[mt], acc[mt], 0, 0, 0);
    }

    // ---- per-lane channel params (c = 16*mt + col)
    float bl[8], gl[8], el[8];
    #pragma unroll
    for (int mt = 0; mt < 8; ++mt) {
        const int c = 16 * mt + col;
        bl[mt] = bp[c]; gl[mt] = gp[c]; el[mt] = bep[c];
    }

    // ---- bias + per-s LayerNorm over c (in-reg over mt, cross-lane over col)
    #pragma unroll
    for (int mt = 0; mt < 8; ++mt)
        #pragma unroll
        for (int r = 0; r < 4; ++r) acc[mt][r] += bl[mt];

    float mean[4], rstd[4];
    #pragma unroll
    for (int r = 0; r < 4; ++r) {
        float s = 0.f, q = 0.f;
        #pragma unroll
        for (int mt = 0; mt < 8; ++mt) {
            float y = acc[mt][r];
            s += y; q += y * y;
        }
        s += __shfl_xor(s, 1); q += __shfl_xor(q, 1);
        s += __shfl_xor(s, 2); q += __shfl_xor(q, 2);
        s += __shfl_xor(s, 4); q += __shfl_xor(q, 4);
        s += __shfl_xor(s, 8); q += __shfl_xor(q, 8);
        float m = s * (1.0f / C);
        float v = q * (1.0f / C) - m * m;
        mean[r] = m;
        rstd[r] = rsqrtf(v + 1e-5f);
    }

    // ---- scale/shift + nontemporal f4 stores (4 consecutive s at fixed c)
    const int sg = s0 + 16 * w + 4 * quad;   // mult of 4; SEQ mult of 4
    if (sg < SEQ) {
        #pragma unroll
        for (int mt = 0; mt < 8; ++mt) {
            const int c = 16 * mt + col;
            f4 v;
            #pragma unroll
            for (int r = 0; r < 4; ++r)
                v[r] = (acc[mt][r] - mean[r]) * rstd[r] * gl[mt] + el[mt];
            __builtin_nontemporal_store(v, (f4*)&og[(size_t)c * SEQ + sg]);
        }
    }
}

extern "C" void kernel_launch(void* const* d_in, const int* in_sizes, int n_in,
                              void* d_out, int out_size, void* d_ws, size_t ws_size,
                              hipStream_t stream) {
    // inputs: x, Wq, bq, gq, betaq, Wk, bk, gk, betak, Wp, bp, gp, betap
    const float* x   = (const float*)d_in[0];
    const float* Wp  = (const float*)d_in[9];
    const float* bp  = (const float*)d_in[10];
    const float* gp  = (const float*)d_in[11];
    const float* bep = (const float*)d_in[12];
    float* out = (float*)d_out;
    unsigned short* wbf = (unsigned short*)d_ws;   // 32 KB bf16 weights

    hipLaunchKernelGGL(cvt_wp, dim3(64), dim3(256), 0, stream, Wp, wbf);

    dim3 grid(NBLK, NG);
    hipLaunchKernelGGL(gemm_ln_mfma, grid, dim3(256), 0, stream,
                       x, wbf, bp, gp, bep, out);
}

// Round 3
// 374.144 us; speedup vs baseline: 1.2609x; 1.2609x over previous
//
#include <hip/hip_runtime.h>

// channel_attention: einsum('bocs,bocm->bocs', x, softmax(score)) contracts m which
// only appears in score => multiplies x by softmax row-sum == 1 (within fp32 eps).
// So q/k/atten are dead code and the problem is exactly:
//   out[g,c,s] = LN_c( sum_m Wp[c][m] * x[g][m][s] + bp[c] ) * gp[c] + betap[c]
// g = b*o in [0,128). Per group: GEMM M=C=128, N=3000, K=128, + per-column LN.
//
// V4. Lesson from V2/V3 (transaction counting): W-from-global = 2048 L1 gather
// line-touches/block and c-major f4 stores = 4x partial-line scatter (WRITE
// inflated 192->250 MB). V1's patterns were right: W via ds_read, stores with
// s-in-lanes (16 lanes x 4B = full 64B sector per instr, WRITE exact). V1's only
// defect: 8 waves/CU. Fix here: 512-thread blocks, NT=128 -> same 64 KB LDS but
// 16 waves/CU (50% occ, 2x V1). Keep V2's cvt_pk bf16 conversion. cvt_wp now
// pre-swizzles W so GEMM W-staging is a pure linear uint4 copy.

#define C    128
#define SEQ  3000
#define NG   128
#define NT   128                       // columns per block
#define NBLK ((SEQ + NT - 1) / NT)     // 24

typedef float f4 __attribute__((ext_vector_type(4)));
typedef short short8 __attribute__((ext_vector_type(8)));

__device__ __forceinline__ unsigned short f2bf(float f) {
    union { float f; unsigned u; } v; v.f = f;
    unsigned r = v.u + 0x7fffu + ((v.u >> 16) & 1u);   // RNE
    return (unsigned short)(r >> 16);
}

// packed f32x2 -> bf16x2, RNE; dst.lo = bf16(lo), dst.hi = bf16(hi)
__device__ __forceinline__ unsigned cvt2(float lo, float hi) {
    unsigned r;
    asm("v_cvt_pk_bf16_f32 %0, %1, %2" : "=v"(r) : "v"(lo), "v"(hi));
    return r;
}

// 16B-chunk XOR swizzle: injective over 16 consecutive rows (frag reads) and over
// the transpose-write lane pattern, both verified <=2-way (V1-proven).
__device__ __forceinline__ int swz(int row, int chunk) {
    return chunk ^ ((row ^ (row >> 2)) & 15);
}

// Writes W in bf16 with the LDS swizzle pre-applied, so the GEMM kernel's
// W-staging is a linear copy.
__global__ void cvt_wp(const float* __restrict__ Wp, unsigned short* __restrict__ out) {
    int i = blockIdx.x * 256 + threadIdx.x;
    if (i >= C * C) return;
    int c = i >> 7, r = i & 127, ch = r >> 3, j = r & 7;
    out[c * C + swz(c, ch) * 8 + j] = f2bf(Wp[i]);
}

__global__ __launch_bounds__(512, 4) void gemm_ln_mfma(
    const float* __restrict__ x,             // [NG][C][SEQ] fp32
    const unsigned short* __restrict__ wbf,  // [C][C] bf16, swizzled chunk layout
    const float* __restrict__ bp,
    const float* __restrict__ gp,
    const float* __restrict__ bep,
    float* __restrict__ out)                 // [NG][C][SEQ] fp32
{
    __shared__ __align__(16) unsigned short Wl[C * C];   // 32 KB, [c][m] swizzled
    __shared__ __align__(16) unsigned short Xl[NT * C];  // 32 KB, [s][m] swizzled

    const int g  = blockIdx.y;
    const int s0 = blockIdx.x * NT;
    const float* xg = x + (size_t)g * (C * SEQ);
    float* og = out + (size_t)g * (C * SEQ);
    const int t = threadIdx.x;

    // ---- stage W: linear uint4 copy (swizzle pre-applied by cvt_wp)
    {
        const uint4* wsrc = (const uint4*)wbf;
        uint4* wdst = (uint4*)Wl;
        #pragma unroll
        for (int i = 0; i < 4; ++i) wdst[t + 512 * i] = wsrc[t + 512 * i];
    }

    // ---- stage X transposed: thread owns (m-chunk, s-quad); 8x4 in-register
    // transpose; single batch of 8 f4 loads, 4 x 16B LDS writes.
    {
        const int sq  = t & 31;              // s-quad 0..31 (consecutive lanes -> coalesced)
        const int mc  = t >> 5;              // m-chunk 0..15
        const int s_loc  = 4 * sq;
        const int s_glob = s0 + s_loc;
        const bool valid = (s_glob + 3) < SEQ;   // SEQ%4==0 -> quad all-or-nothing
        f4 r[8];
        const float* xp = xg + (size_t)(mc * 8) * SEQ + s_glob;
        #pragma unroll
        for (int rr = 0; rr < 8; ++rr) {
            if (valid) r[rr] = *(const f4*)(xp + (size_t)rr * SEQ);
            else       r[rr] = (f4){0.f, 0.f, 0.f, 0.f};
        }
        #pragma unroll
        for (int j = 0; j < 4; ++j) {
            const int sl = s_loc + j;
            uint4 pk;
            pk.x = cvt2(r[0][j], r[1][j]);
            pk.y = cvt2(r[2][j], r[3][j]);
            pk.z = cvt2(r[4][j], r[5][j]);
            pk.w = cvt2(r[6][j], r[7][j]);
            *(uint4*)&Xl[sl * C + swz(sl, mc) * 8] = pk;
        }
    }
    __syncthreads();

    // ---- MFMA: 8 waves, wave owns 16-s strip x all 128 channels (LN in-wave).
    // D = W x X^T: col(lane&15) = s, row(4*quad+r) = c. Stores put s in lanes ->
    // full-sector writes.
    const int w    = t >> 6;
    const int lane = t & 63;
    const int col  = lane & 15;
    const int quad = lane >> 4;

    f4 acc[8];   // [mt = c-tile]
    #pragma unroll
    for (int mt = 0; mt < 8; ++mt) acc[mt] = (f4){0.f, 0.f, 0.f, 0.f};

    const int srow = 16 * w + col;

    #pragma unroll 1
    for (int kc = 0; kc < 4; ++kc) {
        short8 xb = *(const short8*)&Xl[srow * C + swz(srow, 4 * kc + quad) * 8];
        short8 a[8];
        #pragma unroll
        for (int mt = 0; mt < 8; ++mt) {
            const int row = 16 * mt + col;
            a[mt] = *(const short8*)&Wl[row * C + swz(row, 4 * kc + quad) * 8];
        }
        #pragma unroll
        for (int mt = 0; mt < 8; ++mt)
            acc[mt] = __builtin_amdgcn_mfma_f32_16x16x32_bf16(a[mt], xb, acc[mt], 0, 0, 0);
    }

    // ---- bias + in-wave per-column (per-s) LayerNorm; rows of a column span quads
    #pragma unroll
    for (int mt = 0; mt < 8; ++mt) {
        const f4 b4 = *(const f4*)(bp + 16 * mt + 4 * quad);
        #pragma unroll
        for (int r = 0; r < 4; ++r) acc[mt][r] += b4[r];
    }

    float s = 0.f, q = 0.f;
    #pragma unroll
    for (int mt = 0; mt < 8; ++mt)
        #pragma unroll
        for (int r = 0; r < 4; ++r) {
            float y = acc[mt][r];
            s += y; q += y * y;
        }
    s += __shfl_xor(s, 16); q += __shfl_xor(q, 16);
    s += __shfl_xor(s, 32); q += __shfl_xor(q, 32);
    const float mean = s * (1.0f / C);
    const float var  = q * (1.0f / C) - mean * mean;
    const float rstd = rsqrtf(var + 1e-5f);

    // ---- scale/shift + store: 16 lanes x 4B contiguous = full 64B sector/instr
    const int sg = s0 + srow;
    if (sg < SEQ) {
        #pragma unroll
        for (int mt = 0; mt < 8; ++mt) {
            const f4 g4 = *(const f4*)(gp  + 16 * mt + 4 * quad);
            const f4 e4 = *(const f4*)(bep + 16 * mt + 4 * quad);
            #pragma unroll
            for (int r = 0; r < 4; ++r) {
                const int c = 16 * mt + 4 * quad + r;
                og[(size_t)c * SEQ + sg] =
                    (acc[mt][r] - mean) * rstd * g4[r] + e4[r];
            }
        }
    }
}

extern "C" void kernel_launch(void* const* d_in, const int* in_sizes, int n_in,
                              void* d_out, int out_size, void* d_ws, size_t ws_size,
                              hipStream_t stream) {
    // inputs: x, Wq, bq, gq, betaq, Wk, bk, gk, betak, Wp, bp, gp, betap
    const float* x   = (const float*)d_in[0];
    const float* Wp  = (const float*)d_in[9];
    const float* bp  = (const float*)d_in[10];
    const float* gp  = (const float*)d_in[11];
    const float* bep = (const float*)d_in[12];
    float* out = (float*)d_out;
    unsigned short* wbf = (unsigned short*)d_ws;   // 32 KB bf16 weights (swizzled)

    hipLaunchKernelGGL(cvt_wp, dim3(64), dim3(256), 0, stream, Wp, wbf);

    dim3 grid(NBLK, NG);
    hipLaunchKernelGGL(gemm_ln_mfma, grid, dim3(512), 0, stream,
                       x, wbf, bp, gp, bep, out);
}